// Round 3
// baseline (49.294 us; speedup 1.0000x reference)
//
#include <hip/hip_runtime.h>
#include <hip/hip_bf16.h>

#define NN 7
#define HH 16
#define RR 64
#define CC 8
#define NBINS (NN * RR * NN)   // 3136

#define HIST_BLOCK 1024
#define HIST_GRID  512

// ---------------------------------------------------------------------------
// Kernel 0: zero the global bins (replaces hipMemsetAsync -> rocclr fill,
// which cost ~39 us in-graph).
// ---------------------------------------------------------------------------
__global__ __launch_bounds__(256) void rgcn_zero(int* __restrict__ gbins) {
    const int4 z = make_int4(0, 0, 0, 0);
    int4* g4 = reinterpret_cast<int4*>(gbins);
    for (int i = threadIdx.x; i < NBINS / 4; i += 256) g4[i] = z;  // 3136 = 784*4
}

// ---------------------------------------------------------------------------
// Kernel 1: histogram edges into (dst, rel, src) bins. Integer atomics ->
// exactly deterministic. Pipelined int4 loads; rotated global flush.
// ---------------------------------------------------------------------------
__global__ __launch_bounds__(HIST_BLOCK) void rgcn_hist(
    const int* __restrict__ src, const int* __restrict__ dst,
    const int* __restrict__ et, int E, int* __restrict__ gbins) {
    __shared__ int bins[NBINS];
    for (int i = threadIdx.x; i < NBINS; i += blockDim.x) bins[i] = 0;
    __syncthreads();

    const int tid = blockIdx.x * blockDim.x + threadIdx.x;
    const int stride = gridDim.x * blockDim.x;
    const int E4 = E >> 2;
    const int4* s4 = reinterpret_cast<const int4*>(src);
    const int4* d4 = reinterpret_cast<const int4*>(dst);
    const int4* t4 = reinterpret_cast<const int4*>(et);

    int i = tid;
    if (i < E4) {
        int4 s = s4[i], d = d4[i], t = t4[i];
        for (;;) {
            const int ni = i + stride;
            const bool more = ni < E4;
            int4 s2, d2, t2;
            if (more) { s2 = s4[ni]; d2 = d4[ni]; t2 = t4[ni]; }  // prefetch
            atomicAdd(&bins[d.x * (RR * NN) + t.x * NN + s.x], 1);
            atomicAdd(&bins[d.y * (RR * NN) + t.y * NN + s.y], 1);
            atomicAdd(&bins[d.z * (RR * NN) + t.z * NN + s.z], 1);
            atomicAdd(&bins[d.w * (RR * NN) + t.w * NN + s.w], 1);
            if (!more) break;
            s = s2; d = d2; t = t2; i = ni;
        }
    }
    // scalar tail (E not multiple of 4)
    for (int e = (E4 << 2) + tid; e < E; e += stride) {
        atomicAdd(&bins[dst[e] * (RR * NN) + et[e] * NN + src[e]], 1);
    }

    __syncthreads();
    // rotated flush: spread same-address atomic pressure across cachelines
    int rot = (blockIdx.x * 997) % NBINS;
    for (int i2 = threadIdx.x; i2 < NBINS; i2 += blockDim.x) {
        int idx = i2 + rot;
        if (idx >= NBINS) idx -= NBINS;
        int v = bins[idx];
        if (v) atomicAdd(&gbins[idx], v);
    }
}

// ---------------------------------------------------------------------------
// Kernel 2: everything else, single block of 512. W1/W2 staged into LDS.
// ---------------------------------------------------------------------------
__global__ __launch_bounds__(512) void rgcn_finish(
    const int* __restrict__ gbins,
    const float* __restrict__ W1,    // [R][N][H]
    const float* __restrict__ root1, // [N][H]
    const float* __restrict__ b1,    // [H]
    const float* __restrict__ W2,    // [R][H][C]
    const float* __restrict__ root2, // [H][C]
    const float* __restrict__ b2,    // [C]
    float* __restrict__ out) {       // [N][C]
    __shared__ int   craw[NN][RR][NN];
    __shared__ float cntf[NN][RR][NN];  // cnt * (1/max(tot,1))
    __shared__ float w1s[RR * NN * HH]; // 7168 floats
    __shared__ float w2s[RR * HH * CC]; // 8192 floats
    __shared__ float h[NN][HH];
    __shared__ float hr[NN][RR][CC];    // hr[src][r][c]
    __shared__ float o[NN][CC];

    const int t = threadIdx.x;
    // stage everything (coalesced), single barrier
    for (int i = t; i < NBINS; i += blockDim.x)
        reinterpret_cast<int*>(craw)[i] = gbins[i];
    const float4* W1v = reinterpret_cast<const float4*>(W1);
    for (int i = t; i < RR * NN * HH / 4; i += blockDim.x)
        reinterpret_cast<float4*>(w1s)[i] = W1v[i];
    const float4* W2v = reinterpret_cast<const float4*>(W2);
    for (int i = t; i < RR * HH * CC / 4; i += blockDim.x)
        reinterpret_cast<float4*>(w2s)[i] = W2v[i];
    __syncthreads();

    // per-(dst, rel) totals -> normalized counts
    for (int i = t; i < NN * RR; i += blockDim.x) {
        int n = i / RR, r = i % RR;
        int tot = 0;
        for (int s = 0; s < NN; ++s) tot += craw[n][r][s];
        float inv = 1.0f / (float)(tot > 0 ? tot : 1);
        for (int s = 0; s < NN; ++s) cntf[n][r][s] = (float)craw[n][r][s] * inv;
    }
    __syncthreads();

    // layer 1: h[n][j] = relu(root1 + b1 + sum_{r,s} cntf * W1[r][s][j])
    for (int i = t; i < NN * HH; i += blockDim.x) {
        int n = i / HH, j = i % HH;
        float acc = root1[n * HH + j] + b1[j];
        for (int r = 0; r < RR; ++r)
            for (int s = 0; s < NN; ++s)
                acc = fmaf(cntf[n][r][s], w1s[(r * NN + s) * HH + j], acc);
        h[n][j] = fmaxf(acc, 0.0f);
    }
    __syncthreads();

    // hr[s][r][c] = sum_j h[s][j] * W2[r][j][c]
    for (int i = t; i < NN * RR * CC; i += blockDim.x) {
        int s = i / (RR * CC);
        int rem = i % (RR * CC);
        int r = rem / CC, c = rem % CC;
        float acc = 0.0f;
        for (int j = 0; j < HH; ++j)
            acc = fmaf(h[s][j], w2s[(r * HH + j) * CC + c], acc);
        hr[s][r][c] = acc;
    }
    __syncthreads();

    // layer 2: out[n][c] = b2 + h[n]@root2 + sum_{r,s} cntf[n][r][s]*hr[s][r][c]
    for (int i = t; i < NN * CC; i += blockDim.x) {
        int n = i / CC, c = i % CC;
        float acc = b2[c];
        for (int j = 0; j < HH; ++j)
            acc = fmaf(h[n][j], root2[j * CC + c], acc);
        for (int r = 0; r < RR; ++r)
            for (int s = 0; s < NN; ++s)
                acc = fmaf(cntf[n][r][s], hr[s][r][c], acc);
        o[n][c] = acc;
    }
    __syncthreads();

    // row-wise log_softmax, one thread per node
    if (t < NN) {
        float m = -1e30f;
        for (int c = 0; c < CC; ++c) m = fmaxf(m, o[t][c]);
        float sum = 0.0f;
        for (int c = 0; c < CC; ++c) sum += __expf(o[t][c] - m);
        float lse = m + __logf(sum);
        for (int c = 0; c < CC; ++c) out[t * CC + c] = o[t][c] - lse;
    }
}

extern "C" void kernel_launch(void* const* d_in, const int* in_sizes, int n_in,
                              void* d_out, int out_size, void* d_ws, size_t ws_size,
                              hipStream_t stream) {
    // input order: x, edge_index, edge_type, W1, root1, b1, W2, root2, b2
    const int* edge_index = (const int*)d_in[1];
    const int* edge_type  = (const int*)d_in[2];
    const float* W1    = (const float*)d_in[3];
    const float* root1 = (const float*)d_in[4];
    const float* b1    = (const float*)d_in[5];
    const float* W2    = (const float*)d_in[6];
    const float* root2 = (const float*)d_in[7];
    const float* b2    = (const float*)d_in[8];
    float* out = (float*)d_out;

    const int E = in_sizes[2];              // num edges
    const int* src = edge_index;            // edge_index[0]
    const int* dst = edge_index + E;        // edge_index[1]

    int* gbins = (int*)d_ws;

    rgcn_zero<<<1, 256, 0, stream>>>(gbins);
    rgcn_hist<<<HIST_GRID, HIST_BLOCK, 0, stream>>>(src, dst, edge_type, E, gbins);
    rgcn_finish<<<1, 512, 0, stream>>>(gbins, W1, root1, b1, W2, root2, b2, out);
}

// Round 4
// 43.034 us; speedup vs baseline: 1.1455x; 1.1455x over previous
//
#include <hip/hip_runtime.h>
#include <hip/hip_bf16.h>

#define NN 7
#define HH 16
#define RR 64
#define CC 8
#define NBINS (NN * RR * NN)   // 3136

#define HIST_BLOCK 1024
#define HIST_GRID  512         // 2 blocks/CU, exactly fills 524288 thread slots

// ---------------------------------------------------------------------------
// Kernel 1: histogram edges into (dst, rel, src) bins in LDS, then write the
// block-private histogram to its own slice of d_ws with PLAIN coalesced
// stores (no device atomics, no zeroing needed). Depth-2 load pipeline.
// ---------------------------------------------------------------------------
__global__ __launch_bounds__(HIST_BLOCK) void rgcn_hist(
    const int* __restrict__ src, const int* __restrict__ dst,
    const int* __restrict__ et, int E, int* __restrict__ part) {
    __shared__ int bins[NBINS];
    for (int i = threadIdx.x; i < NBINS; i += blockDim.x) bins[i] = 0;
    __syncthreads();

    const int tid = blockIdx.x * blockDim.x + threadIdx.x;
    const int stride = gridDim.x * blockDim.x;
    const int E4 = E >> 2;
    const int4* s4 = reinterpret_cast<const int4*>(src);
    const int4* d4 = reinterpret_cast<const int4*>(dst);
    const int4* t4 = reinterpret_cast<const int4*>(et);

    int iA = tid;
    if (iA < E4) {
        // pipeline: A in hand, B in flight, C issued inside loop
        int4 sA = s4[iA], dA = d4[iA], tA = t4[iA];
        int iB = iA + stride;
        bool hasB = iB < E4;
        int4 sB, dB, tB;
        if (hasB) { sB = s4[iB]; dB = d4[iB]; tB = t4[iB]; }
        for (;;) {
            const int iC = iB + stride;
            const bool hasC = hasB && (iC < E4);
            int4 sC, dC, tC;
            if (hasC) { sC = s4[iC]; dC = d4[iC]; tC = t4[iC]; }
            atomicAdd(&bins[dA.x * (RR * NN) + tA.x * NN + sA.x], 1);
            atomicAdd(&bins[dA.y * (RR * NN) + tA.y * NN + sA.y], 1);
            atomicAdd(&bins[dA.z * (RR * NN) + tA.z * NN + sA.z], 1);
            atomicAdd(&bins[dA.w * (RR * NN) + tA.w * NN + sA.w], 1);
            if (!hasB) break;
            sA = sB; dA = dB; tA = tB;
            sB = sC; dB = dC; tB = tC;
            iB = iC; hasB = hasC;
        }
    }
    // scalar tail (E not multiple of 4; E=8M -> never runs, kept for safety)
    for (int e = (E4 << 2) + tid; e < E; e += stride) {
        atomicAdd(&bins[dst[e] * (RR * NN) + et[e] * NN + src[e]], 1);
    }

    __syncthreads();
    // plain coalesced store of the whole private histogram (incl. zeros)
    int* myslice = part + blockIdx.x * NBINS;
    for (int i = threadIdx.x; i < NBINS; i += blockDim.x)
        myslice[i] = bins[i];
}

// ---------------------------------------------------------------------------
// Kernel 1b: reduce 512 partial histograms -> gbins. 49 blocks x 256 thr,
// each block owns 64 bins; 4 chunks of 128 partials per bin, LDS tree.
// Integer sums in fixed order -> deterministic & exact.
// ---------------------------------------------------------------------------
__global__ __launch_bounds__(256) void rgcn_reduce(
    const int* __restrict__ part, int* __restrict__ gbins) {
    __shared__ int acc[4][64];
    const int lane = threadIdx.x & 63;   // bin within block's group
    const int chunk = threadIdx.x >> 6;  // 0..3
    const int bin = blockIdx.x * 64 + lane;  // 49*64 = 3136 exactly

    int s = 0;
    const int p0 = chunk * (HIST_GRID / 4);
#pragma unroll 8
    for (int k = 0; k < HIST_GRID / 4; ++k)
        s += part[(p0 + k) * NBINS + bin];
    acc[chunk][lane] = s;
    __syncthreads();
    if (chunk == 0)
        gbins[bin] = acc[0][lane] + acc[1][lane] + acc[2][lane] + acc[3][lane];
}

// ---------------------------------------------------------------------------
// Kernel 2: everything else, single block of 512. W1/W2 staged into LDS.
// ---------------------------------------------------------------------------
__global__ __launch_bounds__(512) void rgcn_finish(
    const int* __restrict__ gbins,
    const float* __restrict__ W1,    // [R][N][H]
    const float* __restrict__ root1, // [N][H]
    const float* __restrict__ b1,    // [H]
    const float* __restrict__ W2,    // [R][H][C]
    const float* __restrict__ root2, // [H][C]
    const float* __restrict__ b2,    // [C]
    float* __restrict__ out) {       // [N][C]
    __shared__ int   craw[NN][RR][NN];
    __shared__ float cntf[NN][RR][NN];  // cnt * (1/max(tot,1))
    __shared__ float w1s[RR * NN * HH]; // 7168 floats
    __shared__ float w2s[RR * HH * CC]; // 8192 floats
    __shared__ float h[NN][HH];
    __shared__ float hr[NN][RR][CC];    // hr[src][r][c]
    __shared__ float o[NN][CC];

    const int t = threadIdx.x;
    // stage everything (coalesced), single barrier
    for (int i = t; i < NBINS; i += blockDim.x)
        reinterpret_cast<int*>(craw)[i] = gbins[i];
    const float4* W1v = reinterpret_cast<const float4*>(W1);
    for (int i = t; i < RR * NN * HH / 4; i += blockDim.x)
        reinterpret_cast<float4*>(w1s)[i] = W1v[i];
    const float4* W2v = reinterpret_cast<const float4*>(W2);
    for (int i = t; i < RR * HH * CC / 4; i += blockDim.x)
        reinterpret_cast<float4*>(w2s)[i] = W2v[i];
    __syncthreads();

    // per-(dst, rel) totals -> normalized counts
    for (int i = t; i < NN * RR; i += blockDim.x) {
        int n = i / RR, r = i % RR;
        int tot = 0;
        for (int s = 0; s < NN; ++s) tot += craw[n][r][s];
        float inv = 1.0f / (float)(tot > 0 ? tot : 1);
        for (int s = 0; s < NN; ++s) cntf[n][r][s] = (float)craw[n][r][s] * inv;
    }
    __syncthreads();

    // layer 1: h[n][j] = relu(root1 + b1 + sum_{r,s} cntf * W1[r][s][j])
    for (int i = t; i < NN * HH; i += blockDim.x) {
        int n = i / HH, j = i % HH;
        float acc = root1[n * HH + j] + b1[j];
        for (int r = 0; r < RR; ++r)
            for (int s = 0; s < NN; ++s)
                acc = fmaf(cntf[n][r][s], w1s[(r * NN + s) * HH + j], acc);
        h[n][j] = fmaxf(acc, 0.0f);
    }
    __syncthreads();

    // hr[s][r][c] = sum_j h[s][j] * W2[r][j][c]
    for (int i = t; i < NN * RR * CC; i += blockDim.x) {
        int s = i / (RR * CC);
        int rem = i % (RR * CC);
        int r = rem / CC, c = rem % CC;
        float acc = 0.0f;
        for (int j = 0; j < HH; ++j)
            acc = fmaf(h[s][j], w2s[(r * HH + j) * CC + c], acc);
        hr[s][r][c] = acc;
    }
    __syncthreads();

    // layer 2: out[n][c] = b2 + h[n]@root2 + sum_{r,s} cntf[n][r][s]*hr[s][r][c]
    for (int i = t; i < NN * CC; i += blockDim.x) {
        int n = i / CC, c = i % CC;
        float acc = b2[c];
        for (int j = 0; j < HH; ++j)
            acc = fmaf(h[n][j], root2[j * CC + c], acc);
        for (int r = 0; r < RR; ++r)
            for (int s = 0; s < NN; ++s)
                acc = fmaf(cntf[n][r][s], hr[s][r][c], acc);
        o[n][c] = acc;
    }
    __syncthreads();

    // row-wise log_softmax, one thread per node
    if (t < NN) {
        float m = -1e30f;
        for (int c = 0; c < CC; ++c) m = fmaxf(m, o[t][c]);
        float sum = 0.0f;
        for (int c = 0; c < CC; ++c) sum += __expf(o[t][c] - m);
        float lse = m + __logf(sum);
        for (int c = 0; c < CC; ++c) out[t * CC + c] = o[t][c] - lse;
    }
}

extern "C" void kernel_launch(void* const* d_in, const int* in_sizes, int n_in,
                              void* d_out, int out_size, void* d_ws, size_t ws_size,
                              hipStream_t stream) {
    // input order: x, edge_index, edge_type, W1, root1, b1, W2, root2, b2
    const int* edge_index = (const int*)d_in[1];
    const int* edge_type  = (const int*)d_in[2];
    const float* W1    = (const float*)d_in[3];
    const float* root1 = (const float*)d_in[4];
    const float* b1    = (const float*)d_in[5];
    const float* W2    = (const float*)d_in[6];
    const float* root2 = (const float*)d_in[7];
    const float* b2    = (const float*)d_in[8];
    float* out = (float*)d_out;

    const int E = in_sizes[2];              // num edges
    const int* src = edge_index;            // edge_index[0]
    const int* dst = edge_index + E;        // edge_index[1]

    int* part  = (int*)d_ws;                       // 512 * 3136 ints = 6.4 MB
    int* gbins = part + HIST_GRID * NBINS;         // 3136 ints

    rgcn_hist<<<HIST_GRID, HIST_BLOCK, 0, stream>>>(src, dst, edge_type, E, part);
    rgcn_reduce<<<49, 256, 0, stream>>>(part, gbins);
    rgcn_finish<<<1, 512, 0, stream>>>(gbins, W1, root1, b1, W2, root2, b2, out);
}

// Round 5
// 39.935 us; speedup vs baseline: 1.2344x; 1.0776x over previous
//
#include <hip/hip_runtime.h>
#include <hip/hip_bf16.h>

#define NN 7
#define HH 16
#define RR 64
#define CC 8
#define NBINS (NN * RR * NN)   // 3136

#define HIST_BLOCK 1024
#define HIST_GRID  256                      // exactly 1 block per CU
#define NT (HIST_GRID * HIST_BLOCK)         // 262144 threads

// ---------------------------------------------------------------------------
// Kernel 1: histogram edges into (dst, rel, src) bins in LDS.
// Branchless depth-4 pipeline: 12 dwordx4 loads in flight, then 16 LDS
// atomics. Block-private histogram stored with plain coalesced stores.
// ---------------------------------------------------------------------------
#define ATOMS(s, d, t)                                         \
    atomicAdd(&bins[(d).x * (RR * NN) + (t).x * NN + (s).x], 1); \
    atomicAdd(&bins[(d).y * (RR * NN) + (t).y * NN + (s).y], 1); \
    atomicAdd(&bins[(d).z * (RR * NN) + (t).z * NN + (s).z], 1); \
    atomicAdd(&bins[(d).w * (RR * NN) + (t).w * NN + (s).w], 1);

__global__ __launch_bounds__(HIST_BLOCK) void rgcn_hist(
    const int* __restrict__ src, const int* __restrict__ dst,
    const int* __restrict__ et, int E, int* __restrict__ part) {
    __shared__ int bins[NBINS];
    for (int i = threadIdx.x; i < NBINS; i += HIST_BLOCK) bins[i] = 0;
    __syncthreads();

    const int tid = blockIdx.x * HIST_BLOCK + threadIdx.x;
    const int E4 = E >> 2;
    const int4* s4 = reinterpret_cast<const int4*>(src);
    const int4* d4 = reinterpret_cast<const int4*>(dst);
    const int4* t4 = reinterpret_cast<const int4*>(et);

    int i = tid;
    // main: 4 triples per body, 12 loads issued before any use
    for (; i + 3 * NT < E4; i += 4 * NT) {
        int4 sa = s4[i],          da = d4[i],          ta = t4[i];
        int4 sb = s4[i + NT],     db = d4[i + NT],     tb = t4[i + NT];
        int4 sc = s4[i + 2 * NT], dc = d4[i + 2 * NT], tc = t4[i + 2 * NT];
        int4 sd = s4[i + 3 * NT], dd = d4[i + 3 * NT], td = t4[i + 3 * NT];
        ATOMS(sa, da, ta)
        ATOMS(sb, db, tb)
        ATOMS(sc, dc, tc)
        ATOMS(sd, dd, td)
    }
    // remainder int4 triples (0..3 per thread)
    for (; i < E4; i += NT) {
        int4 s = s4[i], d = d4[i], t = t4[i];
        ATOMS(s, d, t)
    }
    // scalar tail (E not multiple of 4)
    for (int e = (E4 << 2) + tid; e < E; e += NT) {
        atomicAdd(&bins[dst[e] * (RR * NN) + et[e] * NN + src[e]], 1);
    }

    __syncthreads();
    // plain coalesced store of the whole private histogram (incl. zeros)
    int* myslice = part + blockIdx.x * NBINS;
    for (int i2 = threadIdx.x; i2 < NBINS; i2 += HIST_BLOCK)
        myslice[i2] = bins[i2];
}

// ---------------------------------------------------------------------------
// Kernel 1b: reduce HIST_GRID partial histograms -> gbins. 49 blocks x 256
// threads; each block owns 64 bins; 4 chunks of HIST_GRID/4 partials per bin.
// Integer sums, fixed order -> deterministic & exact.
// ---------------------------------------------------------------------------
__global__ __launch_bounds__(256) void rgcn_reduce(
    const int* __restrict__ part, int* __restrict__ gbins) {
    __shared__ int acc[4][64];
    const int lane = threadIdx.x & 63;
    const int chunk = threadIdx.x >> 6;      // 0..3
    const int bin = blockIdx.x * 64 + lane;  // 49*64 = 3136 exactly

    int s = 0;
    const int p0 = chunk * (HIST_GRID / 4);
#pragma unroll 8
    for (int k = 0; k < HIST_GRID / 4; ++k)
        s += part[(p0 + k) * NBINS + bin];
    acc[chunk][lane] = s;
    __syncthreads();
    if (chunk == 0)
        gbins[bin] = acc[0][lane] + acc[1][lane] + acc[2][lane] + acc[3][lane];
}

// ---------------------------------------------------------------------------
// Kernel 2: everything else, single block of 512. W1/W2 staged into LDS.
// Long serial FMA chains split across threads with LDS partial reduces.
// ---------------------------------------------------------------------------
__global__ __launch_bounds__(512) void rgcn_finish(
    const int* __restrict__ gbins,
    const float* __restrict__ W1,    // [R][N][H]
    const float* __restrict__ root1, // [N][H]
    const float* __restrict__ b1,    // [H]
    const float* __restrict__ W2,    // [R][H][C]
    const float* __restrict__ root2, // [H][C]
    const float* __restrict__ b2,    // [C]
    float* __restrict__ out) {       // [N][C]
    __shared__ int   craw[NN][RR][NN];
    __shared__ float cntf[NN][RR][NN];
    __shared__ float w1s[RR * NN * HH]; // 7168 floats
    __shared__ float w2s[RR * HH * CC]; // 8192 floats
    __shared__ float p1[NN][HH][4];
    __shared__ float h[NN][HH];
    __shared__ float hr[NN][RR][CC];    // hr[src][r][c]
    __shared__ float p2[NN][CC][8];
    __shared__ float o[NN][CC];

    const int t = threadIdx.x;
    // stage everything (coalesced), single barrier
    for (int i = t; i < NBINS; i += blockDim.x)
        reinterpret_cast<int*>(craw)[i] = gbins[i];
    const float4* W1v = reinterpret_cast<const float4*>(W1);
    for (int i = t; i < RR * NN * HH / 4; i += blockDim.x)
        reinterpret_cast<float4*>(w1s)[i] = W1v[i];
    const float4* W2v = reinterpret_cast<const float4*>(W2);
    for (int i = t; i < RR * HH * CC / 4; i += blockDim.x)
        reinterpret_cast<float4*>(w2s)[i] = W2v[i];
    __syncthreads();

    // per-(dst, rel) totals -> normalized counts
    for (int i = t; i < NN * RR; i += blockDim.x) {
        int n = i / RR, r = i % RR;
        int tot = 0;
        for (int s = 0; s < NN; ++s) tot += craw[n][r][s];
        float inv = 1.0f / (float)(tot > 0 ? tot : 1);
        for (int s = 0; s < NN; ++s) cntf[n][r][s] = (float)craw[n][r][s] * inv;
    }
    __syncthreads();

    // layer 1 partials: (n,j,q), q sums r in [16q,16q+16)  — 448 threads
    for (int i = t; i < NN * HH * 4; i += blockDim.x) {
        int n = i >> 6;            // HH*4 = 64
        int j = (i >> 2) & (HH - 1);
        int q = i & 3;
        float acc = 0.0f;
        for (int r = q * 16; r < q * 16 + 16; ++r)
            for (int s = 0; s < NN; ++s)
                acc = fmaf(cntf[n][r][s], w1s[(r * NN + s) * HH + j], acc);
        p1[n][j][q] = acc;
    }
    __syncthreads();
    // layer 1 combine: h = relu(root1 + b1 + sum_q p1)
    for (int i = t; i < NN * HH; i += blockDim.x) {
        int n = i / HH, j = i % HH;
        float acc = root1[n * HH + j] + b1[j] +
                    p1[n][j][0] + p1[n][j][1] + p1[n][j][2] + p1[n][j][3];
        h[n][j] = fmaxf(acc, 0.0f);
    }
    __syncthreads();

    // hr[s][r][c] = sum_j h[s][j] * W2[r][j][c]   — 3584 outputs
    for (int i = t; i < NN * RR * CC; i += blockDim.x) {
        int s = i / (RR * CC);
        int rem = i % (RR * CC);
        int r = rem / CC, c = rem % CC;
        float acc = 0.0f;
        for (int j = 0; j < HH; ++j)
            acc = fmaf(h[s][j], w2s[(r * HH + j) * CC + c], acc);
        hr[s][r][c] = acc;
    }
    __syncthreads();

    // layer 2 partials: (n,c,q), q sums r in [8q,8q+8); q==0 adds root+bias
    for (int i = t; i < NN * CC * 8; i += blockDim.x) {
        int n = i >> 6;            // CC*8 = 64
        int c = (i >> 3) & (CC - 1);
        int q = i & 7;
        float acc = 0.0f;
        for (int r = q * 8; r < q * 8 + 8; ++r)
            for (int s = 0; s < NN; ++s)
                acc = fmaf(cntf[n][r][s], hr[s][r][c], acc);
        if (q == 0) {
            for (int j = 0; j < HH; ++j)
                acc = fmaf(h[n][j], root2[j * CC + c], acc);
            acc += b2[c];
        }
        p2[n][c][q] = acc;
    }
    __syncthreads();
    // layer 2 combine
    for (int i = t; i < NN * CC; i += blockDim.x) {
        int n = i / CC, c = i % CC;
        float acc = 0.0f;
        for (int q = 0; q < 8; ++q) acc += p2[n][c][q];
        o[n][c] = acc;
    }
    __syncthreads();

    // row-wise log_softmax, one thread per node
    if (t < NN) {
        float m = -1e30f;
        for (int c = 0; c < CC; ++c) m = fmaxf(m, o[t][c]);
        float sum = 0.0f;
        for (int c = 0; c < CC; ++c) sum += __expf(o[t][c] - m);
        float lse = m + __logf(sum);
        for (int c = 0; c < CC; ++c) out[t * CC + c] = o[t][c] - lse;
    }
}

extern "C" void kernel_launch(void* const* d_in, const int* in_sizes, int n_in,
                              void* d_out, int out_size, void* d_ws, size_t ws_size,
                              hipStream_t stream) {
    // input order: x, edge_index, edge_type, W1, root1, b1, W2, root2, b2
    const int* edge_index = (const int*)d_in[1];
    const int* edge_type  = (const int*)d_in[2];
    const float* W1    = (const float*)d_in[3];
    const float* root1 = (const float*)d_in[4];
    const float* b1    = (const float*)d_in[5];
    const float* W2    = (const float*)d_in[6];
    const float* root2 = (const float*)d_in[7];
    const float* b2    = (const float*)d_in[8];
    float* out = (float*)d_out;

    const int E = in_sizes[2];              // num edges
    const int* src = edge_index;            // edge_index[0]
    const int* dst = edge_index + E;        // edge_index[1]

    int* part  = (int*)d_ws;                       // 256 * 3136 ints = 3.2 MB
    int* gbins = part + HIST_GRID * NBINS;         // 3136 ints

    rgcn_hist<<<HIST_GRID, HIST_BLOCK, 0, stream>>>(src, dst, edge_type, E, part);
    rgcn_reduce<<<49, 256, 0, stream>>>(part, gbins);
    rgcn_finish<<<1, 512, 0, stream>>>(gbins, W1, root1, b1, W2, root2, b2, out);
}